// Round 13
// baseline (74.707 us; speedup 1.0000x reference)
//
#include <hip/hip_runtime.h>
#include <hip/hip_bf16.h>

#define NROWS 8192
#define DCOLS 256
#define NBLK2 544    // sum_{p=0}^{63} ceil((64-p)/4); 544 % 8 == 0
constexpr float EPSV = 1e-6f;
constexpr float FP8_SCALE = 16.0f;
constexpr float GRAM_FIX = 2.0f / (FP8_SCALE * FP8_SCALE);

typedef __attribute__((ext_vector_type(4))) float f32x4;
typedef __attribute__((ext_vector_type(2))) long long ll2;

__device__ __forceinline__ void async16(void* lds, const void* g) {
    __builtin_amdgcn_global_load_lds(
        (const __attribute__((address_space(1))) void*)g,
        (__attribute__((address_space(3))) void*)lds, 16, 0, 0);
}

#define SBAR() do { __builtin_amdgcn_sched_barrier(0); __builtin_amdgcn_s_barrier(); \
                    __builtin_amdgcn_sched_barrier(0); } while (0)
#define VMWAIT(N) asm volatile("s_waitcnt vmcnt(" #N ")" ::: "memory")

// ---------------- K12: row norms + per-block colsum partials ----------------
__global__ void k12_fused(const float* __restrict__ in, float* __restrict__ inv,
                          float* __restrict__ part) {
    int t = threadIdx.x, lane = t & 63, wave = t >> 6;
    int r0 = blockIdx.x * 32;
    __shared__ float cs[4][256];
    float4 acc4 = {0.f, 0.f, 0.f, 0.f};
    #pragma unroll
    for (int rr = 0; rr < 8; ++rr) {
        int row = r0 + wave * 8 + rr;
        float4 v = *reinterpret_cast<const float4*>(&in[row * DCOLS + lane * 4]);
        float s = v.x * v.x + v.y * v.y + v.z * v.z + v.w * v.w;
        #pragma unroll
        for (int o = 1; o < 64; o <<= 1) s += __shfl_xor(s, o);
        float iv = 1.0f / (sqrtf(s) + EPSV);
        if (lane == 0) inv[row] = iv;
        acc4.x += v.x * iv; acc4.y += v.y * iv; acc4.z += v.z * iv; acc4.w += v.w * iv;
    }
    *reinterpret_cast<float4*>(&cs[wave][lane * 4]) = acc4;
    __syncthreads();
    part[blockIdx.x * 256 + t] = cs[0][t] + cs[1][t] + cs[2][t] + cs[3][t];
}

// ---------------- K3: colmean; center; write PACKED fp8 (x16); sq_norms ----------------
// Packed row layout (256B/row): byte(k) = (k>>6)*64 + (((k&31)>>3)<<4) + ((k>>5)&1)*8 + (k&7)
// -> 16B granule s*4+y holds kk=2s (lo 8B) and kk=2s+1 (hi 8B) for k-subrange y.
__global__ void k3_center(const float* __restrict__ in, const float* __restrict__ inv,
                          const float* __restrict__ part,
                          unsigned char* __restrict__ cf8, float* __restrict__ sqn) {
    int t = threadIdx.x, lane = t & 63, wave = t >> 6;
    int r0 = blockIdx.x * 32;
    __shared__ float cm[256];
    float m = 0.f;
    #pragma unroll 8
    for (int b = 0; b < 256; ++b) m += part[b * 256 + t];
    cm[t] = m * (1.0f / NROWS);
    __syncthreads();
    float4 m4 = *reinterpret_cast<const float4*>(&cm[lane * 4]);
    int k0 = lane * 4;
    int s4 = k0 >> 6, kp = k0 & 63, h = kp >> 5, kpp = kp & 31;
    int pos = s4 * 64 + ((kpp >> 3) << 4) + h * 8 + (kpp & 7);   // per-lane constant
    #pragma unroll
    for (int rr = 0; rr < 8; ++rr) {
        int row = r0 + wave * 8 + rr;
        float iv = inv[row];
        float4 v = *reinterpret_cast<const float4*>(&in[row * DCOLS + k0]);
        float4 cv = {v.x * iv - m4.x, v.y * iv - m4.y, v.z * iv - m4.z, v.w * iv - m4.w};
        int pk = __builtin_amdgcn_cvt_pk_fp8_f32(cv.x * FP8_SCALE, cv.y * FP8_SCALE, 0, false);
        pk = __builtin_amdgcn_cvt_pk_fp8_f32(cv.z * FP8_SCALE, cv.w * FP8_SCALE, pk, true);
        *reinterpret_cast<int*>(&cf8[row * DCOLS + pos]) = pk;
        float s = cv.x * cv.x + cv.y * cv.y + cv.z * cv.z + cv.w * cv.w;
        #pragma unroll
        for (int o = 1; o < 64; o <<= 1) s += __shfl_xor(s, o);
        if (lane == 0) sqn[row] = s;
    }
}

// ---------------- K4: panel-resident. Block = (p, q-chunk of 4). A panel (128x256B) ----------------
// LDS-resident full-K; B panels double-buffered full-K. 1 barrier per tile.
// Swizzle: LDS[r][granule g] = src[r][g ^ (r&15)] (16B granules, involution both sides).
__global__ __launch_bounds__(512, 2) void k4_dist(const unsigned char* __restrict__ cf8,
                                                  const float* __restrict__ sqn,
                                                  float* __restrict__ partial) {
    __shared__ unsigned char As[128 * 256];      // 32KB
    __shared__ unsigned char Bs[2][128 * 256];   // 64KB
    __shared__ float sqA[128];
    __shared__ float red8[8];

    int bid = blockIdx.x;
    int idx = (bid & 7) * (NBLK2 / 8) + (bid >> 3);   // XCD swizzle
    int rem = idx, p = 0;
    while (true) { int nc = (67 - p) >> 2; if (rem < nc) break; rem -= nc; ++p; }
    int q0 = p + rem * 4;
    int nt = 64 - q0; if (nt > 4) nt = 4;

    int t = threadIdx.x, lane = t & 63, wave = t >> 6;
    int wr = wave >> 2, wc = wave & 3;            // 2x4 wave grid: 64x32 out each
    int rl = lane & 15, y = lane >> 4;
    int Rw = wave * 16;
    int brow = p * 128;

    const char* gbase = (const char*)cf8;
    size_t aRowOff = (size_t)(brow + Rw + y) * 256;   // + c*1024
    size_t bRowOff = (size_t)(Rw + y) * 256;          // + q*32768 + c*1024
    int g0 = rl ^ y;

    // hoisted LDS read offsets (per-lane constants)
    int aOff[4][4], bOff[2][4];
    #pragma unroll
    for (int s = 0; s < 4; ++s) {
        int gs = ((s * 4 + y) ^ rl) << 4;
        #pragma unroll
        for (int m = 0; m < 4; ++m)
            aOff[m][s] = (wr * 64 + m * 16 + rl) * 256 + gs;
        #pragma unroll
        for (int n = 0; n < 2; ++n)
            bOff[n][s] = (wc * 32 + n * 16 + rl) * 256 + gs;
    }

    // prologue: stage A panel + B(q0) + sqA
    #pragma unroll
    for (int c = 0; c < 4; ++c) {
        int gsw = (g0 ^ (4 * c)) << 4;
        async16(&As[(Rw + 4 * c) * 256], gbase + aRowOff + c * 1024 + gsw);
        async16(&Bs[0][(Rw + 4 * c) * 256],
                gbase + (size_t)q0 * 32768 + bRowOff + c * 1024 + gsw);
    }
    if (t < 128) sqA[t] = sqn[brow + t];
    __syncthreads();

    float tsum = 0.0f;

    for (int i = 0; i < nt; ++i) {
        int q = q0 + i;
        if (i + 1 < nt) {   // stage next B under this tile's compute
            #pragma unroll
            for (int c = 0; c < 4; ++c) {
                int gsw = (g0 ^ (4 * c)) << 4;
                async16(&Bs[(i + 1) & 1][(Rw + 4 * c) * 256],
                        gbase + (size_t)(q + 1) * 32768 + bRowOff + c * 1024 + gsw);
            }
        }
        const unsigned char* Br = Bs[i & 1];

        f32x4 acc[4][2] = {};
        #pragma unroll
        for (int s = 0; s < 4; ++s) {
            ll2 a[4], b[2];
            #pragma unroll
            for (int m = 0; m < 4; ++m)
                a[m] = *reinterpret_cast<const ll2*>(&As[0] + aOff[m][s]);
            #pragma unroll
            for (int n = 0; n < 2; ++n)
                b[n] = *reinterpret_cast<const ll2*>(Br + bOff[n][s]);
            #pragma unroll
            for (int m = 0; m < 4; ++m)
                #pragma unroll
                for (int n = 0; n < 2; ++n) {
                    acc[m][n] = __builtin_amdgcn_mfma_f32_16x16x32_fp8_fp8(a[m].x, b[n].x, acc[m][n], 0, 0, 0);
                    acc[m][n] = __builtin_amdgcn_mfma_f32_16x16x32_fp8_fp8(a[m].y, b[n].y, acc[m][n], 0, 0, 0);
                }
        }

        // epilogue: accumulate sqrt distances into register (no per-tile reduce)
        float local = 0.0f;
        #pragma unroll
        for (int n = 0; n < 2; ++n) {
            float sj = sqn[q * 128 + wc * 32 + n * 16 + rl];
            #pragma unroll
            for (int m = 0; m < 4; ++m) {
                int i0 = wr * 64 + m * 16 + y * 4;
                #pragma unroll
                for (int r = 0; r < 4; ++r) {
                    float sq = sqA[i0 + r] + sj - GRAM_FIX * acc[m][n][r];
                    local += (sq > 0.0f) ? sqrtf(sq) : 0.0f;
                }
            }
        }
        tsum += ((q == p) ? 1.0f : 2.0f) * local;

        VMWAIT(0);      // next-B staged (issued a full tile ago: near-zero wait)
        SBAR();         // everyone done reading Br; buffer swap safe
    }

    #pragma unroll
    for (int o = 1; o < 64; o <<= 1) tsum += __shfl_xor(tsum, o);
    if (lane == 0) red8[wave] = tsum;
    __syncthreads();
    if (t == 0) {
        float s8 = 0.f;
        #pragma unroll
        for (int i = 0; i < 8; ++i) s8 += red8[i];
        partial[idx] = s8;
    }
}

// ---------------- K5: final scalar ----------------
__global__ void k5_final(const float* __restrict__ sqn, const float* __restrict__ partial,
                         float* __restrict__ out) {
    int t = threadIdx.x;
    int lane = t & 63, wave = t >> 6;
    float s = 0.0f;
    for (int r = t; r < NROWS; r += 1024) s += sqn[r];
    double ds = 0.0;
    for (int r = t; r < NBLK2; r += 1024) ds += (double)partial[r];
    #pragma unroll
    for (int o = 1; o < 64; o <<= 1) { s += __shfl_xor(s, o); ds += __shfl_xor(ds, o); }
    __shared__ float redf[16];
    __shared__ double redd[16];
    if (lane == 0) { redf[wave] = s; redd[wave] = ds; }
    __syncthreads();
    if (t == 0) {
        float sumsq = 0.f; double sd = 0.0;
        #pragma unroll
        for (int i = 0; i < 16; ++i) { sumsq += redf[i]; sd += redd[i]; }
        double md = sd / ((double)NROWS * (double)NROWS);
        out[0] = (float)DCOLS / sumsq + (float)log(md);
    }
}

extern "C" void kernel_launch(void* const* d_in, const int* in_sizes, int n_in,
                              void* d_out, int out_size, void* d_ws, size_t ws_size,
                              hipStream_t stream) {
    const float* emb = (const float*)d_in[0];
    float* out = (float*)d_out;
    char* ws = (char*)d_ws;

    float*  inv     = (float*)ws;                    // 8192 f32
    float*  sqn     = (float*)(ws + 36864);          // 8192 f32
    float*  partial = (float*)(ws + 69632);          // 544 f32
    float*  part    = (float*)(ws + 81920);          // 256*256 f32 = 256KB
    unsigned char* cf8 = (unsigned char*)(ws + 81920 + 262144); // 2 MB packed fp8

    k12_fused <<<NROWS / 32, 256, 0, stream>>>(emb, inv, part);
    k3_center <<<NROWS / 32, 256, 0, stream>>>(emb, inv, part, cf8, sqn);
    k4_dist   <<<NBLK2, 512, 0, stream>>>(cf8, sqn, partial);
    k5_final  <<<1, 1024, 0, stream>>>(sqn, partial, out);
}

// Round 14
// 50.894 us; speedup vs baseline: 1.4679x; 1.4679x over previous
//
#include <hip/hip_runtime.h>
#include <hip/hip_bf16.h>

#define NROWS 8192
#define DCOLS 256
#define NTILES 2080   // 64*65/2 upper-triangle 128x128 tiles
constexpr float EPSV = 1e-6f;
constexpr float FP8_SCALE = 16.0f;
constexpr float GRAM_FIX = 2.0f / (FP8_SCALE * FP8_SCALE);

typedef __attribute__((ext_vector_type(4))) float f32x4;
typedef __attribute__((ext_vector_type(2))) long long ll2;

__device__ __forceinline__ void async16(void* lds, const void* g) {
    __builtin_amdgcn_global_load_lds(
        (const __attribute__((address_space(1))) void*)g,
        (__attribute__((address_space(3))) void*)lds, 16, 0, 0);
}

#define SBAR() do { __builtin_amdgcn_sched_barrier(0); __builtin_amdgcn_s_barrier(); \
                    __builtin_amdgcn_sched_barrier(0); } while (0)
#define VMWAIT(N) asm volatile("s_waitcnt vmcnt(" #N ")" ::: "memory")

// ---------------- K12: row norms + per-block colsum partials (1024 blocks x 8 rows) ----------------
__global__ void k12_fused(const float* __restrict__ in, float* __restrict__ inv,
                          float* __restrict__ part) {
    int t = threadIdx.x, lane = t & 63, wave = t >> 6;
    int r0 = blockIdx.x * 8;
    __shared__ float cs[4][256];
    float4 acc4 = {0.f, 0.f, 0.f, 0.f};
    #pragma unroll
    for (int rr = 0; rr < 2; ++rr) {
        int row = r0 + wave * 2 + rr;
        float4 v = *reinterpret_cast<const float4*>(&in[row * DCOLS + lane * 4]);
        float s = v.x * v.x + v.y * v.y + v.z * v.z + v.w * v.w;
        #pragma unroll
        for (int o = 1; o < 64; o <<= 1) s += __shfl_xor(s, o);
        float iv = 1.0f / (sqrtf(s) + EPSV);
        if (lane == 0) inv[row] = iv;
        acc4.x += v.x * iv; acc4.y += v.y * iv; acc4.z += v.z * iv; acc4.w += v.w * iv;
    }
    *reinterpret_cast<float4*>(&cs[wave][lane * 4]) = acc4;
    __syncthreads();
    part[blockIdx.x * 256 + t] = cs[0][t] + cs[1][t] + cs[2][t] + cs[3][t];
}

// ---------------- KMID: reduce 1024 partial rows -> 16 ----------------
__global__ void kmid(const float* __restrict__ part, float* __restrict__ part2) {
    int t = threadIdx.x;   // 16 blocks x 256 thr; block b sums rows b*64..b*64+63
    float m = 0.f;
    #pragma unroll 8
    for (int i = 0; i < 64; ++i) m += part[(blockIdx.x * 64 + i) * 256 + t];
    part2[blockIdx.x * 256 + t] = m;
}

// ---------------- K3: colmean; center; write PACKED fp8 (x16); sq_norms (1024 blocks) ----------------
// Packed row layout (256B/row): byte(k) = (k>>6)*64 + (((k&31)>>3)<<4) + ((k>>5)&1)*8 + (k&7)
__global__ void k3_center(const float* __restrict__ in, const float* __restrict__ inv,
                          const float* __restrict__ part2,
                          unsigned char* __restrict__ cf8, float* __restrict__ sqn) {
    int t = threadIdx.x, lane = t & 63, wave = t >> 6;
    int r0 = blockIdx.x * 8;
    __shared__ float cm[256];
    float m = 0.f;
    #pragma unroll
    for (int i = 0; i < 16; ++i) m += part2[i * 256 + t];
    cm[t] = m * (1.0f / NROWS);
    __syncthreads();
    float4 m4 = *reinterpret_cast<const float4*>(&cm[lane * 4]);
    int k0 = lane * 4;
    int s4 = k0 >> 6, kp = k0 & 63, h = kp >> 5, kpp = kp & 31;
    int pos = s4 * 64 + ((kpp >> 3) << 4) + h * 8 + (kpp & 7);
    #pragma unroll
    for (int rr = 0; rr < 2; ++rr) {
        int row = r0 + wave * 2 + rr;
        float iv = inv[row];
        float4 v = *reinterpret_cast<const float4*>(&in[row * DCOLS + k0]);
        float4 cv = {v.x * iv - m4.x, v.y * iv - m4.y, v.z * iv - m4.z, v.w * iv - m4.w};
        int pk = __builtin_amdgcn_cvt_pk_fp8_f32(cv.x * FP8_SCALE, cv.y * FP8_SCALE, 0, false);
        pk = __builtin_amdgcn_cvt_pk_fp8_f32(cv.z * FP8_SCALE, cv.w * FP8_SCALE, pk, true);
        *reinterpret_cast<int*>(&cf8[row * DCOLS + pos]) = pk;
        float s = cv.x * cv.x + cv.y * cv.y + cv.z * cv.z + cv.w * cv.w;
        #pragma unroll
        for (int o = 1; o < 64; o <<= 1) s += __shfl_xor(s, o);
        if (lane == 0) sqn[row] = s;
    }
}

// ---------------- K4: 128x128 fp8 tile, 4 waves (64x64 each), counted-vmcnt dbuf ----------------
__device__ __forceinline__ void compute_slice(const unsigned char* Ar, const unsigned char* Br,
                                              int aBase, int bBase, f32x4 acc[4][4]) {
    ll2 a[4], b[4];
    #pragma unroll
    for (int m = 0; m < 4; ++m)
        a[m] = *reinterpret_cast<const ll2*>(Ar + aBase + m * 1024);
    #pragma unroll
    for (int n = 0; n < 4; ++n)
        b[n] = *reinterpret_cast<const ll2*>(Br + bBase + n * 1024);
    #pragma unroll
    for (int m = 0; m < 4; ++m)
        #pragma unroll
        for (int n = 0; n < 4; ++n) {
            acc[m][n] = __builtin_amdgcn_mfma_f32_16x16x32_fp8_fp8(a[m].x, b[n].x, acc[m][n], 0, 0, 0);
            acc[m][n] = __builtin_amdgcn_mfma_f32_16x16x32_fp8_fp8(a[m].y, b[n].y, acc[m][n], 0, 0, 0);
        }
}

__global__ __launch_bounds__(256, 4) void k4_dist(const unsigned char* __restrict__ cf8,
                                                  const float* __restrict__ sqn,
                                                  float* __restrict__ partial) {
    __shared__ unsigned char As[2][128 * 64];   // 2 x 8KB
    __shared__ unsigned char Bs[2][128 * 64];
    __shared__ float sqA[128], sqB[128];
    __shared__ float red4[4];

    int bid = blockIdx.x;
    int idx = (bid & 7) * (NTILES / 8) + (bid >> 3);
    int q = (int)((sqrtf(8.0f * (float)idx + 1.0f) - 1.0f) * 0.5f);
    while ((q + 1) * (q + 2) / 2 <= idx) ++q;
    while (q * (q + 1) / 2 > idx) --q;
    int p = idx - q * (q + 1) / 2;

    int brow = p * 128, bcol = q * 128;
    int t = threadIdx.x, lane = t & 63, wave = t >> 6;
    int wr = wave >> 1, wc = wave & 1;   // 2x2 grid: 64x64 per wave
    int rl = lane & 15, y = lane >> 4;

    // staging: wave stages 32 rows/slice (2 async16 each for A,B).
    // lane l -> row +(l>>2), granule l&3; source granule (l&3)^((l>>3)&3).
    int Rw = wave * 32;
    int laneOff = ((lane >> 2) * DCOLS) + ((((lane & 3) ^ ((lane >> 3) & 3))) << 4);
    const char* Asrc  = (const char*)cf8 + (size_t)(brow + Rw) * DCOLS + laneOff;
    const char* Asrc2 = Asrc + 16 * DCOLS;
    const char* Bsrc  = (const char*)cf8 + (size_t)(bcol + Rw) * DCOLS + laneOff;
    const char* Bsrc2 = Bsrc + 16 * DCOLS;

    // read addressing (per-lane constants + immediate offsets)
    int xc = y ^ ((rl >> 1) & 3);
    int aBase = (wr * 64 + rl) * 64 + xc * 16;
    int bBase = (wc * 64 + rl) * 64 + xc * 16;

    if (t < 128) sqA[t] = sqn[brow + t];
    else sqB[t - 128] = sqn[bcol + t - 128];

    f32x4 acc[4][4] = {};

#define STAGE(buf, sl) do { \
        async16(&As[buf][Rw * 64],        Asrc  + (sl) * 64); \
        async16(&As[buf][(Rw + 16) * 64], Asrc2 + (sl) * 64); \
        async16(&Bs[buf][Rw * 64],        Bsrc  + (sl) * 64); \
        async16(&Bs[buf][(Rw + 16) * 64], Bsrc2 + (sl) * 64); } while (0)

    STAGE(0, 0);
    STAGE(1, 1);
    __syncthreads();                                   // slices 0,1 + sq staged

    compute_slice(As[0], Bs[0], aBase, bBase, acc);    // s=0
    SBAR();
    STAGE(0, 2);
    compute_slice(As[1], Bs[1], aBase, bBase, acc);    // s=1 (hides stage2)
    SBAR();
    STAGE(1, 3);
    VMWAIT(4);                                         // my stage2 landed
    SBAR();
    compute_slice(As[0], Bs[0], aBase, bBase, acc);    // s=2 (hides stage3)
    VMWAIT(0);                                         // my stage3 landed
    SBAR();
    compute_slice(As[1], Bs[1], aBase, bBase, acc);    // s=3
#undef STAGE

    // epilogue
    float local = 0.0f;
    #pragma unroll
    for (int n = 0; n < 4; ++n) {
        float sj = sqB[wc * 64 + n * 16 + rl];
        #pragma unroll
        for (int m = 0; m < 4; ++m) {
            int i0 = wr * 64 + m * 16 + y * 4;
            #pragma unroll
            for (int r = 0; r < 4; ++r) {
                float sq = sqA[i0 + r] + sj - GRAM_FIX * acc[m][n][r];
                local += (sq > 0.0f) ? sqrtf(sq) : 0.0f;
            }
        }
    }
    #pragma unroll
    for (int o = 1; o < 64; o <<= 1) local += __shfl_xor(local, o);
    if (lane == 0) red4[wave] = local;
    __syncthreads();
    if (t == 0) {
        float w = (p == q) ? 1.0f : 2.0f;
        partial[idx] = w * (red4[0] + red4[1] + red4[2] + red4[3]);
    }
}

// ---------------- K5: final scalar ----------------
__global__ void k5_final(const float* __restrict__ sqn, const float* __restrict__ partial,
                         float* __restrict__ out) {
    int t = threadIdx.x;
    int lane = t & 63, wave = t >> 6;
    float s = 0.0f;
    for (int r = t; r < NROWS; r += 1024) s += sqn[r];
    double ds = 0.0;
    for (int r = t; r < NTILES; r += 1024) ds += (double)partial[r];
    #pragma unroll
    for (int o = 1; o < 64; o <<= 1) { s += __shfl_xor(s, o); ds += __shfl_xor(ds, o); }
    __shared__ float redf[16];
    __shared__ double redd[16];
    if (lane == 0) { redf[wave] = s; redd[wave] = ds; }
    __syncthreads();
    if (t == 0) {
        float sumsq = 0.f; double sd = 0.0;
        #pragma unroll
        for (int i = 0; i < 16; ++i) { sumsq += redf[i]; sd += redd[i]; }
        double md = sd / ((double)NROWS * (double)NROWS);
        out[0] = (float)DCOLS / sumsq + (float)log(md);
    }
}

extern "C" void kernel_launch(void* const* d_in, const int* in_sizes, int n_in,
                              void* d_out, int out_size, void* d_ws, size_t ws_size,
                              hipStream_t stream) {
    const float* emb = (const float*)d_in[0];
    float* out = (float*)d_out;
    char* ws = (char*)d_ws;

    float*  inv     = (float*)ws;                    // 8192 f32
    float*  sqn     = (float*)(ws + 36864);          // 8192 f32
    float*  partial = (float*)(ws + 69632);          // 2080 f32
    float*  part    = (float*)(ws + 81920);          // 1024*256 f32 = 1MB
    float*  part2   = (float*)(ws + 81920 + 1048576);// 16*256 f32
    unsigned char* cf8 = (unsigned char*)(ws + 81920 + 1048576 + 16384); // 2MB packed fp8

    k12_fused <<<1024, 256, 0, stream>>>(emb, inv, part);
    kmid      <<<16, 256, 0, stream>>>(part, part2);
    k3_center <<<1024, 256, 0, stream>>>(emb, inv, part2, cf8, sqn);
    k4_dist   <<<NTILES, 256, 0, stream>>>(cf8, sqn, partial);
    k5_final  <<<1, 1024, 0, stream>>>(sqn, partial, out);
}